// Round 4
// baseline (460.264 us; speedup 1.0000x reference)
//
#include <hip/hip_runtime.h>

#define Bn 4
#define Cn 256
#define HWn 4096
#define CPn 64
#define MP 640   // CW rows padded 576 -> 640 (5 x 128)

typedef unsigned short u16;
typedef unsigned int u32;
typedef unsigned long long u64;

using short8  = __attribute__((ext_vector_type(8))) short;
using floatx4 = __attribute__((ext_vector_type(4))) float;

static __device__ __forceinline__ u16 f2bf(float f) {
    union { float f; u32 u; } v; v.f = f;
    u32 r = (v.u + 0x7FFFu + ((v.u >> 16) & 1u)) >> 16;
    return (u16)r;
}

// async global -> LDS, 16 B per lane. LDS dest = wave-uniform base + lane*16.
static __device__ __forceinline__ void gld16(const u16* g, u16* l) {
    __builtin_amdgcn_global_load_lds(
        (const __attribute__((address_space(1))) u32*)g,
        (__attribute__((address_space(3))) u32*)l, 16, 0, 0);
}

// ---------------------------------------------------------------------------
// Mega-kernel v2: 256 blocks x 1024 threads (16 waves = 4 waves/SIMD).
// 128 KB LDS -> 1 block/CU, all 256 blocks resident -> software barrier safe.
// R3 ran 256 threads (1 wave/SIMD): MfmaUtil 4.8%, VALU 6.5%, HBM 7.8% ->
// pure latency-bound.  This version re-partitions every phase over 4x waves.
// ---------------------------------------------------------------------------
__global__ __launch_bounds__(1024) void mega(
    const float* __restrict__ Tt, const float* __restrict__ Bt, const float* __restrict__ Mt,
    const float* __restrict__ Wqkv, const float* __restrict__ Wred, const float* __restrict__ Wrec,
    u16* __restrict__ xT, u16* __restrict__ CWp,
    float* __restrict__ Psum, float* __restrict__ Pmax,
    float* __restrict__ vout, u16* __restrict__ Mm,
    float* __restrict__ out, u32* __restrict__ gcnt)
{
    __shared__ __align__(16) u16 SM[65536];   // 128 KB, re-aliased per phase
    const int t   = threadIdx.x;
    const int blk = blockIdx.x;
    const int w = t >> 6, lane = t & 63;
    const int l15 = lane & 15, q = lane >> 4;
    const int g  = t >> 8, gt = t & 255;      // 4 groups of 256
    const u32 nb = gridDim.x;

    // device-scope software barrier; distinct counter (own cacheline) per id
    auto gbar = [&](int id) {
        __syncthreads();
        if (t == 0) {
            __threadfence();                       // release prior writes
            atomicAdd(&gcnt[id * 16], 1u);
            int guard = 0;
            while (atomicAdd(&gcnt[id * 16], 0u) < nb && guard < 20000000) {
                __builtin_amdgcn_s_sleep(2);
                ++guard;
            }
            __threadfence();                       // acquire others' writes
        }
        __syncthreads();
    };

    // ===================== Phase A: transpose + compose =====================
    {
        u16 (*T)[72] = (u16(*)[72])(SM + g * 4608);    // 4 x 9216 B
        const int cl = gt >> 2, qq = gt & 3;
        #pragma unroll 1
        for (int pass = 0; pass < 3; ++pass) {
            const int tile = pass * 1024 + blk * 4 + g;   // 3072 tiles total
            const int hwt = tile & 63, ct = (tile >> 6) & 3;
            const int b = (tile >> 8) & 3, s = tile >> 10;
            const int c0 = ct * 64, hw0 = hwt * 64;
            const float* X = (s == 0 ? Tt : (s == 1 ? Bt : Mt)) + (size_t)b * Cn * HWn;
            const float* src = X + (size_t)(c0 + cl) * HWn + hw0 + qq * 16;
            #pragma unroll
            for (int u = 0; u < 4; ++u) {
                const float4 v = *(const float4*)(src + u * 4);
                u64 pk = (u64)f2bf(v.x) | ((u64)f2bf(v.y) << 16) |
                         ((u64)f2bf(v.z) << 32) | ((u64)f2bf(v.w) << 48);
                *(u64*)&T[cl][qq * 16 + u * 4] = pk;
            }
            __syncthreads();
            u16* dst = xT + ((size_t)((s * Bn + b) * HWn) + hw0 + cl) * Cn + c0 + qq * 16;
            #pragma unroll
            for (int u = 0; u < 2; ++u) {
                u32 w0 = (u32)T[qq*16+u*8+0][cl] | ((u32)T[qq*16+u*8+1][cl] << 16);
                u32 w1 = (u32)T[qq*16+u*8+2][cl] | ((u32)T[qq*16+u*8+3][cl] << 16);
                u32 w2 = (u32)T[qq*16+u*8+4][cl] | ((u32)T[qq*16+u*8+5][cl] << 16);
                u32 w3 = (u32)T[qq*16+u*8+6][cl] | ((u32)T[qq*16+u*8+7][cl] << 16);
                uint4 pk4 = {w0, w1, w2, w3};
                *(uint4*)(dst + u * 8) = pk4;
            }
            __syncthreads();
        }

        if (blk < 27) {        // CW compose: 27 blocks x 4 groups (c0 = g*64)
            float (*As)[64]  = (float(*)[64])((char*)SM + g * 8192);
            float (*Bsc)[64] = (float(*)[64])((char*)SM + g * 8192 + 4096);
            const int c0   = g * 64;
            const int y9 = blk % 9, s = blk / 9;
            const int tt = y9 / 3, m3 = y9 % 3;
            const int idx = (tt == 1) ? (3 * s + m3) : (3 * m3 + s);
            const float* A  = Wred + (size_t)idx * CPn * Cn;
            const float* Bm = Wqkv + (size_t)(3 * s + tt) * Cn * Cn;
            const int ty = gt >> 4, tx = gt & 15;
            float acc[4][4] = {};
            for (int k0 = 0; k0 < Cn; k0 += 16) {
                {
                    const int r = gt >> 2, eq = (gt & 3) * 4;
                    const float4 a = *(const float4*)(A + (size_t)r * Cn + k0 + eq);
                    As[eq+0][r]=a.x; As[eq+1][r]=a.y; As[eq+2][r]=a.z; As[eq+3][r]=a.w;
                }
                {
                    const int r = gt >> 4, cq = (gt & 15) * 4;
                    *(float4*)(&Bsc[r][cq]) = *(const float4*)(Bm + (size_t)(k0+r)*Cn + c0 + cq);
                }
                __syncthreads();
                #pragma unroll
                for (int k = 0; k < 16; ++k) {
                    const float4 a4 = *(const float4*)(&As[k][ty*4]);
                    const float4 b4 = *(const float4*)(&Bsc[k][tx*4]);
                    const float a_[4]  = {a4.x, a4.y, a4.z, a4.w};
                    const float bb_[4] = {b4.x, b4.y, b4.z, b4.w};
                    #pragma unroll
                    for (int i2 = 0; i2 < 4; ++i2)
                        #pragma unroll
                        for (int j2 = 0; j2 < 4; ++j2)
                            acc[i2][j2] = fmaf(a_[i2], bb_[j2], acc[i2][j2]);
                }
                __syncthreads();
            }
            u16* outp = CWp + (size_t)s * MP * Cn;
            #pragma unroll
            for (int i2 = 0; i2 < 4; ++i2) {
                const int row = tt * 192 + m3 * 64 + ty * 4 + i2;
                u64 pk = (u64)f2bf(acc[i2][0]) | ((u64)f2bf(acc[i2][1]) << 16) |
                         ((u64)f2bf(acc[i2][2]) << 32) | ((u64)f2bf(acc[i2][3]) << 48);
                *(u64*)(outp + (size_t)row * Cn + c0 + tx * 4) = pk;
            }
        }
    }
    gbar(0);

    // ===================== Phase B: redpool GEMM =====================
    // 480 units = 3 s x 5 mt x 32 nch; 2 units/block (two 8-wave groups).
    // Per unit: A 128x256 in VGPRs, B-chunk 512 cols; 8 subtiles of 64 cols,
    // dbuf 2x32 KB per group; relu+pool in registers.
    if (blk < 240) {
        const int h = w >> 3, v = w & 7;          // group h, wave-in-group v
        const int u = blk * 2 + h;                // unit 0..479
        const int s = u / 160, r160 = u % 160;
        const int mt = r160 >> 5, nch = r160 & 31;
        const int m0 = mt * 128;
        const int nbase = nch * 512;
        const u16* Ap = CWp + (size_t)s * MP * Cn;
        const u16* Bp = xT + (size_t)s * Bn * HWn * Cn;
        const int wr = v >> 2, wc = v & 3;        // row half (64), col quarter (16)

        short8 af[4][8];
        {
            const u16* Arow = Ap + (size_t)(m0 + wr * 64 + l15) * Cn + q * 8;
            #pragma unroll
            for (int i = 0; i < 4; ++i)
                #pragma unroll
                for (int kk = 0; kk < 8; ++kk)
                    af[i][kk] = *(const short8*)(Arow + (size_t)(i * 16) * Cn + kk * 32);
        }

        u16* const LBg = SM + h * 32768;          // per-group 64 KB (2 bufs x 32 KB)
        auto stageB = [&](int it, int buf) {
            u16* dstb = LBg + buf * 16384;
            const u16* Bsrc = Bp + (size_t)(nbase + it * 64 + l15) * Cn + q * 8;
            #pragma unroll
            for (int pi = 0; pi < 4; ++pi) {
                const int p = v * 4 + pi;         // 32 panes: (colblk p>>3, kchunk p&7)
                gld16(Bsrc + (size_t)((p >> 3) * 16) * Cn + (p & 7) * 32, dstb + p * 512);
            }
        };
        stageB(0, 0);

        float rs[4][4] = {};
        float rm[4][4] = {};

        for (int it = 0; it < 8; ++it) {
            __syncthreads();                       // drains B[it]; prev compute done
            if (it + 1 < 8) stageB(it + 1, (it + 1) & 1);
            const u16* bb = LBg + (it & 1) * 16384;

            floatx4 acc[4] = {};
            __builtin_amdgcn_s_setprio(1);
            #pragma unroll
            for (int kk = 0; kk < 8; ++kk) {
                const short8 bf = *(const short8*)&bb[(wc * 8 + kk) * 512 + lane * 8];
                #pragma unroll
                for (int i = 0; i < 4; ++i)
                    acc[i] = __builtin_amdgcn_mfma_f32_16x16x32_bf16(af[i][kk], bf, acc[i], 0, 0, 0);
            }
            __builtin_amdgcn_s_setprio(0);
            #pragma unroll
            for (int i = 0; i < 4; ++i)
                #pragma unroll
                for (int r = 0; r < 4; ++r) {
                    const float v0 = fmaxf(acc[i][r], 0.f);
                    rs[i][r] += v0;
                    rm[i][r] = fmaxf(rm[i][r], v0);
                }
        }

        // reduce over the 16 cols of this wave's quarter
        #pragma unroll
        for (int i = 0; i < 4; ++i)
            #pragma unroll
            for (int r = 0; r < 4; ++r) {
                #pragma unroll
                for (int off = 1; off < 16; off <<= 1) {
                    rs[i][r] += __shfl_xor(rs[i][r], off);
                    rm[i][r] = fmaxf(rm[i][r], __shfl_xor(rm[i][r], off));
                }
            }

        __syncthreads();
        float* Ls = (float*)SM + h * 1024;        // [4 wc][128 rows] sums
        float* Lm = Ls + 512;                     // [4 wc][128 rows] maxes
        if (l15 == 0) {
            #pragma unroll
            for (int i = 0; i < 4; ++i)
                #pragma unroll
                for (int r = 0; r < 4; ++r) {
                    const int row = wr * 64 + i * 16 + q * 4 + r;
                    Ls[wc * 128 + row] = rs[i][r];
                    Lm[wc * 128 + row] = rm[i][r];
                }
        }
        __syncthreads();
        const int th = t - h * 512;               // thread-in-group
        if (th >= 0 && th < 128) {
            const int R = m0 + th;
            const size_t o = ((size_t)s * MP + R) * 32 + nch;
            Psum[o] = (Ls[th] + Ls[128 + th]) + (Ls[256 + th] + Ls[384 + th]);
            Pmax[o] = fmaxf(fmaxf(Lm[th], Lm[128 + th]), fmaxf(Lm[256 + th], Lm[384 + th]));
        }
    }
    gbar(1);

    // ===================== Phase C: tiny attention (36 units) ================
    if (blk < 36) {
        float* ff = (float*)SM;
        float* gg = ff + 64;
        float* hh = ff + 128;
        const int idx = blk >> 2, bb2 = blk & 3;
        if (t < 64) {
            float vv[3];
            #pragma unroll
            for (int tt = 0; tt < 3; ++tt) {
                const int s_ = (tt == 1) ? idx / 3 : idx % 3;
                const int m3 = (tt == 1) ? idx % 3 : idx / 3;
                const int R  = tt * 192 + m3 * 64 + t;
                const size_t base = ((size_t)s_ * MP + R) * 32 + bb2 * 8;
                float sm = 0.f, mx = 0.f;
                #pragma unroll
                for (int u2 = 0; u2 < 8; ++u2) {
                    sm += Psum[base + u2];
                    mx = fmaxf(mx, Pmax[base + u2]);
                }
                vv[tt] = sm * (1.0f / HWn) + mx;
            }
            gg[t] = vv[0];   // Q-pool
            ff[t] = vv[1];   // K-pool
            hh[t] = vv[2];   // V-pool
        }
        __syncthreads();
        if (t < 64) {
            const float gj = gg[t];
            float mx = -1e30f;
            for (int i = 0; i < CPn; ++i) mx = fmaxf(mx, ff[i] * gj);
            float den = 0.f, num = 0.f;
            for (int i = 0; i < CPn; ++i) {
                const float e = expf(ff[i] * gj - mx);
                den += e;
                num += hh[i] * e;
            }
            vout[((size_t)idx * Bn + bb2) * CPn + t] = num / den;
        }
    }
    gbar(2);

    // ===================== Phase D: build Mm (4 groups x 3 units/block) ======
    {
        float* cc = (float*)SM + g * 16;
        #pragma unroll 1
        for (int i = 0; i < 3; ++i) {
            const int unit = blk * 12 + g * 3 + i;  // 3072 = (s*256+m)*4+b
            const int b = unit & 3, m = (unit >> 2) & 255, s = unit >> 10;
            if (gt < CPn) {
                float d[6];
                #pragma unroll
                for (int j = 0; j < 6; ++j) {
                    const int idx = (j < 3) ? (s + 3 * j) : (3 * s + (j - 3));
                    d[j] = vout[((size_t)idx * Bn + b) * CPn + gt] *
                           Wrec[((size_t)idx * Cn + m) * CPn + gt];
                }
                #pragma unroll
                for (int off = 32; off >= 1; off >>= 1)
                    #pragma unroll
                    for (int j = 0; j < 6; ++j)
                        d[j] += __shfl_xor(d[j], off);
                if (gt == 0) {
                    float cA = 0.f, cK = 0.f;
                    #pragma unroll
                    for (int j = 0; j < 3; ++j) {
                        cA += 1.0f / (1.0f + expf(-d[j]));
                        cK += 1.0f / (1.0f + expf(-d[j + 3]));
                    }
                    cc[0] = cA; cc[1] = cK;
                }
            }
            __syncthreads();
            const float cA = cc[0], cK = cc[1];
            const float wq = Wqkv[((size_t)(3 * s + 0) * Cn + m) * Cn + gt];
            const float wk = Wqkv[((size_t)(3 * s + 1) * Cn + m) * Cn + gt];
            const float wv = Wqkv[((size_t)(3 * s + 2) * Cn + m) * Cn + gt];
            Mm[((size_t)(b * 256 + m)) * 768 + s * 256 + gt] = f2bf(cA * (wq + wv) + cK * wk);
            __syncthreads();
        }
    }
    gbar(3);

    // ===================== Phase E: final GEMM (256 units, 16 waves) =========
    {
        const int b  = blk >> 6, rest = blk & 63;
        const int mt = rest >> 5, nt = rest & 31;
        const int m0 = mt * 128, n0 = nt * 128;
        u16* const A0 = SM;            // 2 bufs x 32 KB
        u16* const B0 = SM + 32768;    // 2 bufs x 32 KB
        const int rw = w >> 2, cw = w & 3;   // 4x4 wave grid, 32x32 each

        auto stage = [&](int it, int bufofs) {
            const int k0 = it * 128;
            const int s = k0 >> 8, c0 = k0 & 255;
            const u16* Asrc = Mm + (size_t)(b * 256 + m0 + l15) * 768 + k0 + q * 8;
            const u16* Bsrc = xT + ((size_t)((s * Bn + b) * HWn) + n0 + l15) * Cn + c0 + q * 8;
            #pragma unroll
            for (int pi = 0; pi < 2; ++pi) {
                const int p = w * 2 + pi;         // 32 panes: (rowblk p>>2, kchunk p&3)
                const size_t roff = (size_t)((p >> 2) * 16);
                gld16(Asrc + roff * 768 + (p & 3) * 32, A0 + bufofs + p * 512);
                gld16(Bsrc + roff * Cn + (p & 3) * 32, B0 + bufofs + p * 512);
            }
        };
        stage(0, 0);

        floatx4 acc[2][2] = {};

        for (int it = 0; it < 6; ++it) {
            __syncthreads();
            if (it + 1 < 6) stage(it + 1, ((it + 1) & 1) * 16384);
            const u16* as = A0 + (it & 1) * 16384;
            const u16* bs = B0 + (it & 1) * 16384;
            #pragma unroll
            for (int kk = 0; kk < 4; ++kk) {
                short8 af2[2], bf2[2];
                #pragma unroll
                for (int i = 0; i < 2; ++i)
                    af2[i] = *(const short8*)&as[((rw * 2 + i) * 4 + kk) * 512 + lane * 8];
                #pragma unroll
                for (int j = 0; j < 2; ++j)
                    bf2[j] = *(const short8*)&bs[((cw * 2 + j) * 4 + kk) * 512 + lane * 8];
                #pragma unroll
                for (int i = 0; i < 2; ++i)
                    #pragma unroll
                    for (int j = 0; j < 2; ++j)
                        acc[i][j] = __builtin_amdgcn_mfma_f32_16x16x32_bf16(af2[i], bf2[j], acc[i][j], 0, 0, 0);
            }
        }

        #pragma unroll
        for (int i = 0; i < 2; ++i)
            #pragma unroll
            for (int j = 0; j < 2; ++j)
                #pragma unroll
                for (int r = 0; r < 4; ++r) {
                    const int row = m0 + rw * 32 + i * 16 + q * 4 + r;
                    const int col = n0 + cw * 32 + j * 16 + l15;
                    out[((size_t)(b * 256) + row) * HWn + col] = acc[i][j][r];
                }
    }
}

extern "C" void kernel_launch(void* const* d_in, const int* in_sizes, int n_in,
                              void* d_out, int out_size, void* d_ws, size_t ws_size,
                              hipStream_t stream)
{
    const float* Tt   = (const float*)d_in[0];
    const float* Bt   = (const float*)d_in[1];
    const float* Mt   = (const float*)d_in[2];
    const float* Wqkv = (const float*)d_in[3];
    const float* Wred = (const float*)d_in[4];
    const float* Wrec = (const float*)d_in[5];
    float* out = (float*)d_out;

    unsigned char* p = (unsigned char*)d_ws;
    u16* xT = (u16*)p;            p += (size_t)3 * Bn * HWn * Cn * 2;   // 25.2 MB
    u16* Mm = (u16*)p;            p += (size_t)Bn * 256 * 768 * 2;      // 1.57 MB
    u16* CWp = (u16*)p;           p += (size_t)3 * MP * Cn * 2;         // 983 KB
    float* Psum = (float*)p;      p += (size_t)3 * MP * 32 * 4;         // 246 KB
    float* Pmax = (float*)p;      p += (size_t)3 * MP * 32 * 4;         // 246 KB
    float* vout = (float*)p;      p += (size_t)9 * Bn * CPn * 4;        // 9.2 KB
    u32* gcnt = (u32*)p;          p += 256;                             // barrier counters

    hipMemsetAsync(gcnt, 0, 256, stream);
    mega<<<dim3(256), dim3(1024), 0, stream>>>(Tt, Bt, Mt, Wqkv, Wred, Wrec,
                                               xT, CWp, Psum, Pmax, vout, Mm, out, gcnt);
}

// Round 6
// 287.884 us; speedup vs baseline: 1.5988x; 1.5988x over previous
//
#include <hip/hip_runtime.h>

#define Bn 4
#define Cn 256
#define HWn 4096
#define CPn 64
#define MP 640   // CW rows padded 576 -> 640 (5 x 128)

typedef unsigned short u16;
typedef unsigned int u32;
typedef unsigned long long u64;

using short8  = __attribute__((ext_vector_type(8))) short;
using floatx4 = __attribute__((ext_vector_type(4))) float;

static __device__ __forceinline__ u16 f2bf(float f) {
    union { float f; u32 u; } v; v.f = f;
    u32 r = (v.u + 0x7FFFu + ((v.u >> 16) & 1u)) >> 16;
    return (u16)r;
}

// async global -> LDS, 16 B per lane. LDS dest = wave-uniform base + lane*16.
static __device__ __forceinline__ void gld16(const u16* g, u16* l) {
    __builtin_amdgcn_global_load_lds(
        (const __attribute__((address_space(1))) u32*)g,
        (__attribute__((address_space(3))) u32*)l, 16, 0, 0);
}

// ---------------------------------------------------------------------------
// Mega-kernel v4: 256 blocks x 512 threads (8 waves = 2 waves/SIMD).
// Grid == CU count -> software barrier co-residency trivially safe (R5's
// 512-block grid deadlocked).  __launch_bounds__(512,2) -> 256 VGPR cap,
// no spill (R4's 1024-thread version was capped at 64 VGPR and spilled
// ~560 MB scratch).  128 KB LDS -> 1 block/CU.
// ---------------------------------------------------------------------------
__global__ __launch_bounds__(512, 2) void mega(
    const float* __restrict__ Tt, const float* __restrict__ Bt, const float* __restrict__ Mt,
    const float* __restrict__ Wqkv, const float* __restrict__ Wred, const float* __restrict__ Wrec,
    u16* __restrict__ xT, u16* __restrict__ CWp,
    float* __restrict__ Psum, float* __restrict__ Pmax,
    float* __restrict__ vout, u16* __restrict__ Mm,
    float* __restrict__ out, u32* __restrict__ gcnt)
{
    __shared__ __align__(16) u16 SM[65536];   // 128 KB, re-aliased per phase
    const int t   = threadIdx.x;
    const int blk = blockIdx.x;
    const int w = t >> 6, lane = t & 63;
    const int l15 = lane & 15, q = lane >> 4;
    const int g  = t >> 8, gt = t & 255;      // 2 groups of 256
    const u32 nb = gridDim.x;

    // device-scope software barrier; distinct counter (own cacheline) per id
    auto gbar = [&](int id) {
        __syncthreads();
        if (t == 0) {
            __threadfence();                       // release prior writes
            atomicAdd(&gcnt[id * 16], 1u);
            int guard = 0;
            while (atomicAdd(&gcnt[id * 16], 0u) < nb && guard < 20000000) {
                __builtin_amdgcn_s_sleep(2);
                ++guard;
            }
            __threadfence();                       // acquire others' writes
        }
        __syncthreads();
    };

    // ===================== Phase A: transpose + compose =====================
    {
        u16 (*T)[72] = (u16(*)[72])(SM + g * 4608);    // 2 x 9216 B
        const int cl = gt >> 2, qq = gt & 3;
        #pragma unroll 1
        for (int i = 0; i < 6; ++i) {
            const int tile = blk * 12 + g * 6 + i;       // 3072 tiles total
            const int hwt = tile & 63, ct = (tile >> 6) & 3;
            const int b = (tile >> 8) & 3, s = tile >> 10;
            const int c0 = ct * 64, hw0 = hwt * 64;
            const float* X = (s == 0 ? Tt : (s == 1 ? Bt : Mt)) + (size_t)b * Cn * HWn;
            const float* src = X + (size_t)(c0 + cl) * HWn + hw0 + qq * 16;
            #pragma unroll
            for (int u = 0; u < 4; ++u) {
                const float4 v = *(const float4*)(src + u * 4);
                u64 pk = (u64)f2bf(v.x) | ((u64)f2bf(v.y) << 16) |
                         ((u64)f2bf(v.z) << 32) | ((u64)f2bf(v.w) << 48);
                *(u64*)&T[cl][qq * 16 + u * 4] = pk;
            }
            __syncthreads();
            u16* dst = xT + ((size_t)((s * Bn + b) * HWn) + hw0 + cl) * Cn + c0 + qq * 16;
            #pragma unroll
            for (int u = 0; u < 2; ++u) {
                u32 w0 = (u32)T[qq*16+u*8+0][cl] | ((u32)T[qq*16+u*8+1][cl] << 16);
                u32 w1 = (u32)T[qq*16+u*8+2][cl] | ((u32)T[qq*16+u*8+3][cl] << 16);
                u32 w2 = (u32)T[qq*16+u*8+4][cl] | ((u32)T[qq*16+u*8+5][cl] << 16);
                u32 w3 = (u32)T[qq*16+u*8+6][cl] | ((u32)T[qq*16+u*8+7][cl] << 16);
                uint4 pk4 = {w0, w1, w2, w3};
                *(uint4*)(dst + u * 8) = pk4;
            }
            __syncthreads();
        }

        if (blk < 54) {        // CW compose: 54 blocks x 2 groups = 108 units
            float (*As)[64]  = (float(*)[64])((char*)SM + g * 8192);
            float (*Bsc)[64] = (float(*)[64])((char*)SM + g * 8192 + 4096);
            const int unit = blk * 2 + g;                // 0..107
            const int c0   = (unit & 3) * 64;
            const int rest = unit >> 2;                  // 0..26
            const int y9 = rest % 9, s = rest / 9;
            const int tt = y9 / 3, m3 = y9 % 3;
            const int idx = (tt == 1) ? (3 * s + m3) : (3 * m3 + s);
            const float* A  = Wred + (size_t)idx * CPn * Cn;
            const float* Bm = Wqkv + (size_t)(3 * s + tt) * Cn * Cn;
            const int ty = gt >> 4, tx = gt & 15;
            float acc[4][4] = {};
            for (int k0 = 0; k0 < Cn; k0 += 16) {
                {
                    const int r = gt >> 2, eq = (gt & 3) * 4;
                    const float4 a = *(const float4*)(A + (size_t)r * Cn + k0 + eq);
                    As[eq+0][r]=a.x; As[eq+1][r]=a.y; As[eq+2][r]=a.z; As[eq+3][r]=a.w;
                }
                {
                    const int r = gt >> 4, cq = (gt & 15) * 4;
                    *(float4*)(&Bsc[r][cq]) = *(const float4*)(Bm + (size_t)(k0+r)*Cn + c0 + cq);
                }
                __syncthreads();
                #pragma unroll
                for (int k = 0; k < 16; ++k) {
                    const float4 a4 = *(const float4*)(&As[k][ty*4]);
                    const float4 b4 = *(const float4*)(&Bsc[k][tx*4]);
                    const float a_[4]  = {a4.x, a4.y, a4.z, a4.w};
                    const float bb_[4] = {b4.x, b4.y, b4.z, b4.w};
                    #pragma unroll
                    for (int i2 = 0; i2 < 4; ++i2)
                        #pragma unroll
                        for (int j2 = 0; j2 < 4; ++j2)
                            acc[i2][j2] = fmaf(a_[i2], bb_[j2], acc[i2][j2]);
                }
                __syncthreads();
            }
            u16* outp = CWp + (size_t)s * MP * Cn;
            #pragma unroll
            for (int i2 = 0; i2 < 4; ++i2) {
                const int row = tt * 192 + m3 * 64 + ty * 4 + i2;
                u64 pk = (u64)f2bf(acc[i2][0]) | ((u64)f2bf(acc[i2][1]) << 16) |
                         ((u64)f2bf(acc[i2][2]) << 32) | ((u64)f2bf(acc[i2][3]) << 48);
                *(u64*)(outp + (size_t)row * Cn + c0 + tx * 4) = pk;
            }
        }
    }
    gbar(0);

    // ===================== Phase B: redpool GEMM (R4-verified 8-wave body) ===
    // 480 units = 3 s x 5 mt x 32 nch; 2 passes of 256 blocks.
    // Per unit: A 128x256 in VGPRs; 8 subtiles of 64 cols, dbuf 2x32 KB.
    // 8 waves = 2 row-halves x 4 col-quarters.
    #pragma unroll 1
    for (int pass = 0; pass < 2; ++pass) {
        const int unit = pass * 256 + blk;
        if (unit < 480) {
            const int s = unit / 160, r160 = unit % 160;
            const int mt = r160 >> 5, nch = r160 & 31;
            const int m0 = mt * 128;
            const int nbase = nch * 512;
            const u16* Ap = CWp + (size_t)s * MP * Cn;
            const u16* Bp = xT + (size_t)s * Bn * HWn * Cn;
            const int wr = w >> 2, wc = w & 3;    // row half (64), col quarter (16)

            short8 af[4][8];
            {
                const u16* Arow = Ap + (size_t)(m0 + wr * 64 + l15) * Cn + q * 8;
                #pragma unroll
                for (int i = 0; i < 4; ++i)
                    #pragma unroll
                    for (int kk = 0; kk < 8; ++kk)
                        af[i][kk] = *(const short8*)(Arow + (size_t)(i * 16) * Cn + kk * 32);
            }

            auto stageB = [&](int it, int buf) {
                u16* dstb = SM + buf * 16384;     // 2 bufs x 32 KB
                const u16* Bsrc = Bp + (size_t)(nbase + it * 64 + l15) * Cn + q * 8;
                #pragma unroll
                for (int pi = 0; pi < 4; ++pi) {
                    const int p = w * 4 + pi;     // 32 panes: (colblk p>>3, kchunk p&7)
                    gld16(Bsrc + (size_t)((p >> 3) * 16) * Cn + (p & 7) * 32, dstb + p * 512);
                }
            };
            stageB(0, 0);

            float rs[4][4] = {};
            float rm[4][4] = {};

            for (int it = 0; it < 8; ++it) {
                __syncthreads();                   // drains B[it]; prev compute done
                if (it + 1 < 8) stageB(it + 1, (it + 1) & 1);
                const u16* bb = SM + (it & 1) * 16384;

                floatx4 acc[4] = {};
                __builtin_amdgcn_s_setprio(1);
                #pragma unroll
                for (int kk = 0; kk < 8; ++kk) {
                    const short8 bf = *(const short8*)&bb[(wc * 8 + kk) * 512 + lane * 8];
                    #pragma unroll
                    for (int i = 0; i < 4; ++i)
                        acc[i] = __builtin_amdgcn_mfma_f32_16x16x32_bf16(af[i][kk], bf, acc[i], 0, 0, 0);
                }
                __builtin_amdgcn_s_setprio(0);
                #pragma unroll
                for (int i = 0; i < 4; ++i)
                    #pragma unroll
                    for (int r = 0; r < 4; ++r) {
                        const float v0 = fmaxf(acc[i][r], 0.f);
                        rs[i][r] += v0;
                        rm[i][r] = fmaxf(rm[i][r], v0);
                    }
            }

            // reduce over the 16 cols of this wave's quarter
            #pragma unroll
            for (int i = 0; i < 4; ++i)
                #pragma unroll
                for (int r = 0; r < 4; ++r) {
                    #pragma unroll
                    for (int off = 1; off < 16; off <<= 1) {
                        rs[i][r] += __shfl_xor(rs[i][r], off);
                        rm[i][r] = fmaxf(rm[i][r], __shfl_xor(rm[i][r], off));
                    }
                }

            __syncthreads();
            float* Ls = (float*)SM;               // [4 wc][128 rows] sums
            float* Lm = Ls + 512;                 // [4 wc][128 rows] maxes
            if (l15 == 0) {
                #pragma unroll
                for (int i = 0; i < 4; ++i)
                    #pragma unroll
                    for (int r = 0; r < 4; ++r) {
                        const int row = wr * 64 + i * 16 + q * 4 + r;
                        Ls[wc * 128 + row] = rs[i][r];
                        Lm[wc * 128 + row] = rm[i][r];
                    }
            }
            __syncthreads();
            if (t < 128) {
                const int R = m0 + t;
                const size_t o = ((size_t)s * MP + R) * 32 + nch;
                Psum[o] = (Ls[t] + Ls[128 + t]) + (Ls[256 + t] + Ls[384 + t]);
                Pmax[o] = fmaxf(fmaxf(Lm[t], Lm[128 + t]), fmaxf(Lm[256 + t], Lm[384 + t]));
            }
            __syncthreads();                      // Ls/Lm reads done before next pass's stage
        }
    }
    gbar(1);

    // ===================== Phase C: tiny attention (36 units) ================
    if (blk < 36) {
        float* ff = (float*)SM;
        float* gg = ff + 64;
        float* hh = ff + 128;
        const int idx = blk >> 2, bb2 = blk & 3;
        if (t < 64) {
            float vv[3];
            #pragma unroll
            for (int tt = 0; tt < 3; ++tt) {
                const int s_ = (tt == 1) ? idx / 3 : idx % 3;
                const int m3 = (tt == 1) ? idx % 3 : idx / 3;
                const int R  = tt * 192 + m3 * 64 + t;
                const size_t base = ((size_t)s_ * MP + R) * 32 + bb2 * 8;
                float sm = 0.f, mx = 0.f;
                #pragma unroll
                for (int u2 = 0; u2 < 8; ++u2) {
                    sm += Psum[base + u2];
                    mx = fmaxf(mx, Pmax[base + u2]);
                }
                vv[tt] = sm * (1.0f / HWn) + mx;
            }
            gg[t] = vv[0];   // Q-pool
            ff[t] = vv[1];   // K-pool
            hh[t] = vv[2];   // V-pool
        }
        __syncthreads();
        if (t < 64) {
            const float gj = gg[t];
            float mx = -1e30f;
            for (int i = 0; i < CPn; ++i) mx = fmaxf(mx, ff[i] * gj);
            float den = 0.f, num = 0.f;
            for (int i = 0; i < CPn; ++i) {
                const float e = expf(ff[i] * gj - mx);
                den += e;
                num += hh[i] * e;
            }
            vout[((size_t)idx * Bn + bb2) * CPn + t] = num / den;
        }
    }
    gbar(2);

    // ===================== Phase D: build Mm (2 groups x 6 units/block) ======
    {
        float* cc = (float*)SM + g * 16;
        #pragma unroll 1
        for (int i = 0; i < 6; ++i) {
            const int unit = blk * 12 + g * 6 + i;  // 3072 = (s*256+m)*4+b
            const int b = unit & 3, m = (unit >> 2) & 255, s = unit >> 10;
            if (gt < CPn) {
                float d[6];
                #pragma unroll
                for (int j = 0; j < 6; ++j) {
                    const int idx = (j < 3) ? (s + 3 * j) : (3 * s + (j - 3));
                    d[j] = vout[((size_t)idx * Bn + b) * CPn + gt] *
                           Wrec[((size_t)idx * Cn + m) * CPn + gt];
                }
                #pragma unroll
                for (int off = 32; off >= 1; off >>= 1)
                    #pragma unroll
                    for (int j = 0; j < 6; ++j)
                        d[j] += __shfl_xor(d[j], off);
                if (gt == 0) {
                    float cA = 0.f, cK = 0.f;
                    #pragma unroll
                    for (int j = 0; j < 3; ++j) {
                        cA += 1.0f / (1.0f + expf(-d[j]));
                        cK += 1.0f / (1.0f + expf(-d[j + 3]));
                    }
                    cc[0] = cA; cc[1] = cK;
                }
            }
            __syncthreads();
            const float cA = cc[0], cK = cc[1];
            const float wq = Wqkv[((size_t)(3 * s + 0) * Cn + m) * Cn + gt];
            const float wk = Wqkv[((size_t)(3 * s + 1) * Cn + m) * Cn + gt];
            const float wv = Wqkv[((size_t)(3 * s + 2) * Cn + m) * Cn + gt];
            Mm[((size_t)(b * 256 + m)) * 768 + s * 256 + gt] = f2bf(cA * (wq + wv) + cK * wk);
            __syncthreads();
        }
    }
    gbar(3);

    // ===================== Phase E: final GEMM (256 units, 8 waves) ==========
    // 128x128 tile, BK=128, 6 iters, A+B dbuf (128 KB LDS).  Wave grid
    // 2 rows x 4 cols, 64x32 per wave (acc[4][2]).  Pane layout = R3's.
    {
        const int b  = blk >> 6, rest = blk & 63;
        const int mt = rest >> 5, nt = rest & 31;
        const int m0 = mt * 128, n0 = nt * 128;
        u16* const A0 = SM;            // 2 bufs x 32 KB
        u16* const B0 = SM + 32768;    // 2 bufs x 32 KB
        const int rw = w >> 2, cw = w & 3;   // 2x4 wave grid

        auto stage = [&](int it, int bufofs) {
            const int k0 = it * 128;
            const int s = k0 >> 8, c0 = k0 & 255;
            const u16* Asrc = Mm + (size_t)(b * 256 + m0 + l15) * 768 + k0 + q * 8;
            const u16* Bsrc = xT + ((size_t)((s * Bn + b) * HWn) + n0 + l15) * Cn + c0 + q * 8;
            #pragma unroll
            for (int pi = 0; pi < 4; ++pi) {
                const int p = w * 4 + pi;         // 32 panes: (rowblk p>>2, kchunk p&3)
                const size_t roff = (size_t)((p >> 2) * 16);
                gld16(Asrc + roff * 768 + (p & 3) * 32, A0 + bufofs + p * 512);
                gld16(Bsrc + roff * Cn + (p & 3) * 32, B0 + bufofs + p * 512);
            }
        };
        stage(0, 0);

        floatx4 acc[4][2] = {};

        for (int it = 0; it < 6; ++it) {
            __syncthreads();
            if (it + 1 < 6) stage(it + 1, ((it + 1) & 1) * 16384);
            const u16* as = A0 + (it & 1) * 16384;
            const u16* bs = B0 + (it & 1) * 16384;
            #pragma unroll
            for (int kk = 0; kk < 4; ++kk) {
                short8 af2[4], bf2[2];
                #pragma unroll
                for (int i = 0; i < 4; ++i)
                    af2[i] = *(const short8*)&as[(((rw * 4 + i) << 2) + kk) * 512 + lane * 8];
                #pragma unroll
                for (int j = 0; j < 2; ++j)
                    bf2[j] = *(const short8*)&bs[(((cw * 2 + j) << 2) + kk) * 512 + lane * 8];
                #pragma unroll
                for (int i = 0; i < 4; ++i)
                    #pragma unroll
                    for (int j = 0; j < 2; ++j)
                        acc[i][j] = __builtin_amdgcn_mfma_f32_16x16x32_bf16(af2[i], bf2[j], acc[i][j], 0, 0, 0);
            }
        }

        #pragma unroll
        for (int i = 0; i < 4; ++i)
            #pragma unroll
            for (int j = 0; j < 2; ++j)
                #pragma unroll
                for (int r = 0; r < 4; ++r) {
                    const int row = m0 + rw * 64 + i * 16 + q * 4 + r;
                    const int col = n0 + cw * 32 + j * 16 + l15;
                    out[((size_t)(b * 256) + row) * HWn + col] = acc[i][j][r];
                }
    }
}

extern "C" void kernel_launch(void* const* d_in, const int* in_sizes, int n_in,
                              void* d_out, int out_size, void* d_ws, size_t ws_size,
                              hipStream_t stream)
{
    const float* Tt   = (const float*)d_in[0];
    const float* Bt   = (const float*)d_in[1];
    const float* Mt   = (const float*)d_in[2];
    const float* Wqkv = (const float*)d_in[3];
    const float* Wred = (const float*)d_in[4];
    const float* Wrec = (const float*)d_in[5];
    float* out = (float*)d_out;

    unsigned char* p = (unsigned char*)d_ws;
    u16* xT = (u16*)p;            p += (size_t)3 * Bn * HWn * Cn * 2;   // 25.2 MB
    u16* Mm = (u16*)p;            p += (size_t)Bn * 256 * 768 * 2;      // 1.57 MB
    u16* CWp = (u16*)p;           p += (size_t)3 * MP * Cn * 2;         // 983 KB
    float* Psum = (float*)p;      p += (size_t)3 * MP * 32 * 4;         // 246 KB
    float* Pmax = (float*)p;      p += (size_t)3 * MP * 32 * 4;         // 246 KB
    float* vout = (float*)p;      p += (size_t)9 * Bn * CPn * 4;        // 9.2 KB
    u32* gcnt = (u32*)p;          p += 256;                             // barrier counters

    hipMemsetAsync(gcnt, 0, 256, stream);
    mega<<<dim3(256), dim3(512), 0, stream>>>(Tt, Bt, Mt, Wqkv, Wred, Wrec,
                                              xT, CWp, Psum, Pmax, vout, Mm, out, gcnt);
}

// Round 7
// 211.029 us; speedup vs baseline: 2.1810x; 1.3642x over previous
//
#include <hip/hip_runtime.h>

#define Bn 4
#define Cn 256
#define HWn 4096
#define CPn 64
#define MP 640   // CW rows padded 576 -> 640 (5 x 128)
#define NCH 256  // pooled partial chunks (one per K2' block)

typedef unsigned short u16;
typedef unsigned int u32;
typedef unsigned long long u64;

using short8  = __attribute__((ext_vector_type(8))) short;
using floatx4 = __attribute__((ext_vector_type(4))) float;

static __device__ __forceinline__ u16 f2bf(float f) {
    union { float f; u32 u; } v; v.f = f;
    u32 r = (v.u + 0x7FFFu + ((v.u >> 16) & 1u)) >> 16;
    return (u16)r;
}

// async global -> LDS, 16 B per lane. LDS dest = wave-uniform base + lane*16.
static __device__ __forceinline__ void gld16(const u16* g, u16* l) {
    __builtin_amdgcn_global_load_lds(
        (const __attribute__((address_space(1))) u32*)g,
        (__attribute__((address_space(3))) u32*)l, 16, 0, 0);
}

// Pane: 64 lanes x 16B = 1 KB; lane l = (row l&15, k-quad l>>4).
// Fragment read = base + lane*16B: contiguous, bank-conflict-free.

// ---------------------------------------------------------------------------
// K1: prep.  z<3: fp32 (C x HW) -> bf16 (HW x C) transpose (s=z)  [for K5].
//            z==3: compose CWp[s](640x256) = stack of Wred[idx] @ Wqkv[3s+tt].
// Verbatim R0 (best-verified version).
// ---------------------------------------------------------------------------
__global__ __launch_bounds__(256) void prep(
    const float* __restrict__ Tt, const float* __restrict__ Bt, const float* __restrict__ Mt,
    const float* __restrict__ Wqkv, const float* __restrict__ Wred,
    u16* __restrict__ xT, u16* __restrict__ CWp)
{
    __shared__ __align__(16) u16 T[64][72];
    __shared__ float As[16][64];
    __shared__ float Bs[16][64];
    const int t = threadIdx.x;

    if (blockIdx.z < 3) {
        const int s  = blockIdx.z, b = blockIdx.y;
        const int ct = blockIdx.x & 3, hwt = blockIdx.x >> 2;
        const int c0 = ct * 64, hw0 = hwt * 64;
        const float* X = (s == 0 ? Tt : (s == 1 ? Bt : Mt)) + (size_t)b * Cn * HWn;

        const int cl = t >> 2, q = t & 3;
        const float* src = X + (size_t)(c0 + cl) * HWn + hw0 + q * 16;
        #pragma unroll
        for (int u = 0; u < 4; ++u) {
            const float4 v = *(const float4*)(src + u * 4);
            u64 pk = (u64)f2bf(v.x) | ((u64)f2bf(v.y) << 16) |
                     ((u64)f2bf(v.z) << 32) | ((u64)f2bf(v.w) << 48);
            *(u64*)&T[cl][q * 16 + u * 4] = pk;
        }
        __syncthreads();

        const int wl = t >> 2;
        u16* dst = xT + ((size_t)((s * Bn + b) * HWn) + hw0 + wl) * Cn + c0 + q * 16;
        #pragma unroll
        for (int u = 0; u < 2; ++u) {
            u32 w0 = (u32)T[q * 16 + u * 8 + 0][wl] | ((u32)T[q * 16 + u * 8 + 1][wl] << 16);
            u32 w1 = (u32)T[q * 16 + u * 8 + 2][wl] | ((u32)T[q * 16 + u * 8 + 3][wl] << 16);
            u32 w2 = (u32)T[q * 16 + u * 8 + 4][wl] | ((u32)T[q * 16 + u * 8 + 5][wl] << 16);
            u32 w3 = (u32)T[q * 16 + u * 8 + 6][wl] | ((u32)T[q * 16 + u * 8 + 7][wl] << 16);
            uint4 pk = {w0, w1, w2, w3};
            *(uint4*)(dst + u * 8) = pk;
        }
        return;
    }

    // compose branch: 108 real blocks out of (256,4) slot
    const int lin = blockIdx.y * 256 + blockIdx.x;
    if (lin >= 108) return;
    const int c0  = (lin & 3) * 64;
    const int rest = lin >> 2;           // 0..26
    const int y9 = rest % 9, s = rest / 9;
    const int tt = y9 / 3, m3 = y9 % 3;
    const int idx = (tt == 1) ? (3 * s + m3) : (3 * m3 + s);

    const float* A  = Wred + (size_t)idx * CPn * Cn;
    const float* Bm = Wqkv + (size_t)(3 * s + tt) * Cn * Cn;

    const int ty = t >> 4, tx = t & 15;
    float acc[4][4] = {};

    for (int k0 = 0; k0 < Cn; k0 += 16) {
        {
            const int r = t >> 2, eq = (t & 3) * 4;
            const float4 a = *(const float4*)(A + (size_t)r * Cn + k0 + eq);
            As[eq + 0][r] = a.x; As[eq + 1][r] = a.y; As[eq + 2][r] = a.z; As[eq + 3][r] = a.w;
        }
        {
            const int r = t >> 4, cq = (t & 15) * 4;
            *(float4*)(&Bs[r][cq]) = *(const float4*)(Bm + (size_t)(k0 + r) * Cn + c0 + cq);
        }
        __syncthreads();
        #pragma unroll
        for (int k = 0; k < 16; ++k) {
            const float4 a4 = *(const float4*)(&As[k][ty * 4]);
            const float4 b4 = *(const float4*)(&Bs[k][tx * 4]);
            const float a[4] = {a4.x, a4.y, a4.z, a4.w};
            const float bb[4] = {b4.x, b4.y, b4.z, b4.w};
            #pragma unroll
            for (int i = 0; i < 4; ++i)
                #pragma unroll
                for (int j = 0; j < 4; ++j)
                    acc[i][j] = fmaf(a[i], bb[j], acc[i][j]);
        }
        __syncthreads();
    }

    u16* outp = CWp + (size_t)s * MP * Cn;
    #pragma unroll
    for (int i = 0; i < 4; ++i) {
        const int row = tt * 192 + m3 * 64 + ty * 4 + i;
        unsigned long long pk =
            (unsigned long long)f2bf(acc[i][0]) |
            ((unsigned long long)f2bf(acc[i][1]) << 16) |
            ((unsigned long long)f2bf(acc[i][2]) << 32) |
            ((unsigned long long)f2bf(acc[i][3]) << 48);
        *(unsigned long long*)(outp + (size_t)row * Cn + c0 + tx * 4) = pk;
    }
}

// ---------------------------------------------------------------------------
// K2': redpool with FUSED transpose.  Grid 256 = (b, hw-chunk of 64 rows).
// Per block: for s in 3: transpose x[s][b][:, hw-chunk] fp32 -> bf16 MFMA
// panes in LDS (K1's verified tile transpose, pass-2 writes panes instead of
// global xT); then 5 mt x 1280 block-MFMAs with A streamed from L2-resident
// CWp.  x read ONCE (50 MB total), no xT round trip, no 5x B re-read.
// Waves split M: wave w owns rows w*32..+32 of the 128-row A tile; all waves
// share the full 64-col B panes.  Pool -> Psum/Pmax[s][R][NCH=256].
// ---------------------------------------------------------------------------
__global__ __launch_bounds__(256, 1) void redpool_fused(
    const float* __restrict__ Tt, const float* __restrict__ Bt, const float* __restrict__ Mt,
    const u16* __restrict__ CWp,
    float* __restrict__ Psum, float* __restrict__ Pmax)
{
    __shared__ __align__(16) u16 PN[32 * 512];   // 32 KB: 32 panes x 512 u16
    __shared__ __align__(16) u16 T[64][72];      // 9.2 KB transpose scratch
    const int t = threadIdx.x;
    const int w = t >> 6, lane = t & 63;
    const int l15 = lane & 15, q = lane >> 4;
    const int b = blockIdx.x >> 6, hwt = blockIdx.x & 63;
    const int hw0 = hwt * 64;
    const int cl = t >> 2, qq = t & 3;           // cl 0..63, qq 0..3

    #pragma unroll 1
    for (int s = 0; s < 3; ++s) {
        const float* X = (s == 0 ? Tt : (s == 1 ? Bt : Mt)) + (size_t)b * Cn * HWn;

        // ---- stage: 4 col-tiles of 64 c -> panes ----
        #pragma unroll 1
        for (int ct = 0; ct < 4; ++ct) {
            const float* src = X + (size_t)(ct * 64 + cl) * HWn + hw0 + qq * 16;
            #pragma unroll
            for (int u = 0; u < 4; ++u) {
                const float4 v = *(const float4*)(src + u * 4);
                u64 pk = (u64)f2bf(v.x) | ((u64)f2bf(v.y) << 16) |
                         ((u64)f2bf(v.z) << 32) | ((u64)f2bf(v.w) << 48);
                *(u64*)&T[cl][qq * 16 + u * 4] = pk;
            }
            __syncthreads();
            // pass-2: thread (wl=cl, qq) emits rows wl, cols ct*64+qq*16+u*8
            // pane P = (wl>>4)*8 + c8>>2 ; elem (c8&3)*16 + (wl&15)  (c8 = col/8)
            #pragma unroll
            for (int u = 0; u < 2; ++u) {
                u32 w0 = (u32)T[qq*16+u*8+0][cl] | ((u32)T[qq*16+u*8+1][cl] << 16);
                u32 w1 = (u32)T[qq*16+u*8+2][cl] | ((u32)T[qq*16+u*8+3][cl] << 16);
                u32 w2 = (u32)T[qq*16+u*8+4][cl] | ((u32)T[qq*16+u*8+5][cl] << 16);
                u32 w3 = (u32)T[qq*16+u*8+6][cl] | ((u32)T[qq*16+u*8+7][cl] << 16);
                uint4 pk4 = {w0, w1, w2, w3};
                const int c8 = ct * 8 + qq * 2 + u;
                const int addr = (((cl >> 4) * 8 + (c8 >> 2)) << 9) +
                                 (((c8 & 3) * 16 + (cl & 15)) << 3);
                *(uint4*)&PN[addr] = pk4;
            }
            __syncthreads();
        }

        // ---- compute: 5 mt, A streamed from CWp, B = panes ----
        #pragma unroll 1
        for (int mt = 0; mt < 5; ++mt) {
            const u16* Arow = CWp + (size_t)s * MP * Cn +
                              (size_t)(mt * 128 + w * 32 + l15) * Cn + q * 8;
            short8 af[2][8];
            #pragma unroll
            for (int i = 0; i < 2; ++i)
                #pragma unroll
                for (int kk = 0; kk < 8; ++kk)
                    af[i][kk] = *(const short8*)(Arow + (size_t)(i * 16) * Cn + kk * 32);

            floatx4 acc[2][4] = {};
            __builtin_amdgcn_s_setprio(1);
            #pragma unroll
            for (int kk = 0; kk < 8; ++kk) {
                short8 bf[4];
                #pragma unroll
                for (int j = 0; j < 4; ++j)
                    bf[j] = *(const short8*)&PN[((j * 8 + kk) << 9) + lane * 8];
                #pragma unroll
                for (int i = 0; i < 2; ++i)
                    #pragma unroll
                    for (int j = 0; j < 4; ++j)
                        acc[i][j] = __builtin_amdgcn_mfma_f32_16x16x32_bf16(af[i][kk], bf[j], acc[i][j], 0, 0, 0);
            }
            __builtin_amdgcn_s_setprio(0);

            // pool over cols (4 j-blocks in regs + 16 lanes via shfl)
            #pragma unroll
            for (int i = 0; i < 2; ++i)
                #pragma unroll
                for (int r = 0; r < 4; ++r) {
                    float sm = 0.f, mx = 0.f;
                    #pragma unroll
                    for (int j = 0; j < 4; ++j) {
                        const float v = fmaxf(acc[i][j][r], 0.f);
                        sm += v; mx = fmaxf(mx, v);
                    }
                    #pragma unroll
                    for (int off = 1; off < 16; off <<= 1) {
                        sm += __shfl_xor(sm, off);
                        mx = fmaxf(mx, __shfl_xor(mx, off));
                    }
                    if (l15 == 0) {
                        const int R = mt * 128 + w * 32 + i * 16 + q * 4 + r;
                        const size_t o = ((size_t)s * MP + R) * NCH + blockIdx.x;
                        Psum[o] = sm;
                        Pmax[o] = mx;
                    }
                }
        }
        __syncthreads();   // panes reused by next s
    }
}

// ---------------------------------------------------------------------------
// K3: tiny attention per (idx,b): reduce 64 chunks -> f,g,h -> softmax -> vout.
// 64 threads (1 wave), 36 blocks.
// ---------------------------------------------------------------------------
__global__ __launch_bounds__(64) void attn_small(
    const float* __restrict__ Psum, const float* __restrict__ Pmax,
    float* __restrict__ vout)
{
    const int idx = blockIdx.x / Bn;
    const int bb  = blockIdx.x % Bn;
    __shared__ float ff[CPn], gg[CPn], hh[CPn];
    const int t = threadIdx.x;

    float v[3];
    #pragma unroll
    for (int tt = 0; tt < 3; ++tt) {
        const int s_ = (tt == 1) ? idx / 3 : idx % 3;
        const int m3 = (tt == 1) ? idx % 3 : idx / 3;
        const int R  = tt * 192 + m3 * 64 + t;
        const size_t base = ((size_t)s_ * MP + R) * NCH + bb * 64;
        const float4* P4 = (const float4*)(Psum + base);
        const float4* M4 = (const float4*)(Pmax + base);
        float sm = 0.f, mx = 0.f;
        #pragma unroll
        for (int u = 0; u < 16; ++u) {
            const float4 a = P4[u];
            sm += (a.x + a.y) + (a.z + a.w);
            const float4 c = M4[u];
            mx = fmaxf(mx, fmaxf(fmaxf(c.x, c.y), fmaxf(c.z, c.w)));
        }
        v[tt] = sm * (1.0f / HWn) + mx;
    }
    gg[t] = v[0];   // Q-pool
    ff[t] = v[1];   // K-pool
    hh[t] = v[2];   // V-pool
    __syncthreads();

    const float gj = gg[t];
    float mx = -1e30f;
    for (int i = 0; i < CPn; ++i) mx = fmaxf(mx, ff[i] * gj);
    float den = 0.f, num = 0.f;
    for (int i = 0; i < CPn; ++i) {
        const float e = expf(ff[i] * gj - mx);
        den += e;
        num += hh[i] * e;
    }
    vout[((size_t)idx * Bn + bb) * CPn + t] = num / den;
}

// ---------------------------------------------------------------------------
// K4: build Mm[b][m][s*256+c] bf16, computing coefs inline from vout.
// Verbatim R0.
// ---------------------------------------------------------------------------
__global__ __launch_bounds__(256) void build_M(
    const float* __restrict__ Wqkv, const float* __restrict__ Wrec,
    const float* __restrict__ vout, u16* __restrict__ Mm)
{
    const int s = blockIdx.x >> 8, m = blockIdx.x & 255;
    const int b = blockIdx.y;
    const int t = threadIdx.x;
    __shared__ float cc[2];

    if (t < CPn) {
        float d[6];
        #pragma unroll
        for (int j = 0; j < 6; ++j) {
            const int idx = (j < 3) ? (s + 3 * j) : (3 * s + (j - 3));
            d[j] = vout[((size_t)idx * Bn + b) * CPn + t] *
                   Wrec[((size_t)idx * Cn + m) * CPn + t];
        }
        #pragma unroll
        for (int off = 32; off >= 1; off >>= 1)
            #pragma unroll
            for (int j = 0; j < 6; ++j)
                d[j] += __shfl_xor(d[j], off);
        if (t == 0) {
            float cA = 0.f, cK = 0.f;
            #pragma unroll
            for (int j = 0; j < 3; ++j) {
                cA += 1.0f / (1.0f + expf(-d[j]));
                cK += 1.0f / (1.0f + expf(-d[j + 3]));
            }
            cc[0] = cA; cc[1] = cK;
        }
    }
    __syncthreads();
    const float cA = cc[0], cK = cc[1];
    const float wq = Wqkv[((size_t)(3 * s + 0) * Cn + m) * Cn + t];
    const float wk = Wqkv[((size_t)(3 * s + 1) * Cn + m) * Cn + t];
    const float wv = Wqkv[((size_t)(3 * s + 2) * Cn + m) * Cn + t];
    Mm[((size_t)(b * 256 + m)) * 768 + s * 256 + t] = f2bf(cA * (wq + wv) + cK * wk);
}

// ---------------------------------------------------------------------------
// K5: out[b] (256 x 4096) = Mm[b] (256 x 768) @ xcat[b]^T.   Verbatim R0.
// ---------------------------------------------------------------------------
__global__ __launch_bounds__(256, 1) void final_mfma(
    const u16* __restrict__ xT, const u16* __restrict__ Mm,
    float* __restrict__ out)
{
    const int b  = blockIdx.y;
    const int mt = blockIdx.x >> 5, nt = blockIdx.x & 31;
    const int m0 = mt * 128, n0 = nt * 128;

    __shared__ __align__(16) u16 As[2][32 * 512];
    __shared__ __align__(16) u16 Bs[2][32 * 512];

    const int t = threadIdx.x;
    const int w = t >> 6, lane = t & 63;
    const int l15 = lane & 15, q = lane >> 4;
    const int rb = (w >> 1) * 64, cb = (w & 1) * 64;

    auto stage = [&](int it, int buf) {
        const int k0 = it * 128;
        const int s = k0 >> 8, c0 = k0 & 255;
        const u16* Asrc = Mm + (size_t)(b * 256 + m0 + l15) * 768 + k0 + q * 8;
        const u16* Bsrc = xT + ((size_t)((s * Bn + b) * HWn) + n0 + l15) * Cn + c0 + q * 8;
        #pragma unroll
        for (int pi = 0; pi < 8; ++pi) {
            const int p = w * 8 + pi;
            const size_t roff = (size_t)((p >> 2) * 16);
            gld16(Asrc + roff * 768 + (p & 3) * 32, &As[buf][p * 512]);
            gld16(Bsrc + roff * Cn + (p & 3) * 32, &Bs[buf][p * 512]);
        }
    };
    stage(0, 0);

    floatx4 acc[4][4] = {};

    for (int it = 0; it < 6; ++it) {
        __syncthreads();
        if (it + 1 < 6) stage(it + 1, (it + 1) & 1);
        const u16* as = As[it & 1];
        const u16* bs = Bs[it & 1];
        #pragma unroll
        for (int kk = 0; kk < 4; ++kk) {
            short8 af[4], bf[4];
            #pragma unroll
            for (int i = 0; i < 4; ++i)
                af[i] = *(const short8*)&as[((((w >> 1) * 4 + i) << 2) + kk) * 512 + lane * 8];
            #pragma unroll
            for (int j = 0; j < 4; ++j)
                bf[j] = *(const short8*)&bs[((((w & 1) * 4 + j) << 2) + kk) * 512 + lane * 8];
            #pragma unroll
            for (int i = 0; i < 4; ++i)
                #pragma unroll
                for (int j = 0; j < 4; ++j)
                    acc[i][j] = __builtin_amdgcn_mfma_f32_16x16x32_bf16(af[i], bf[j], acc[i][j], 0, 0, 0);
        }
    }

    #pragma unroll
    for (int i = 0; i < 4; ++i)
        #pragma unroll
        for (int j = 0; j < 4; ++j)
            #pragma unroll
            for (int r = 0; r < 4; ++r) {
                const int row = m0 + rb + i * 16 + q * 4 + r;
                const int col = n0 + cb + j * 16 + l15;
                out[((size_t)(b * 256) + row) * HWn + col] = acc[i][j][r];
            }
}

extern "C" void kernel_launch(void* const* d_in, const int* in_sizes, int n_in,
                              void* d_out, int out_size, void* d_ws, size_t ws_size,
                              hipStream_t stream)
{
    const float* Tt   = (const float*)d_in[0];
    const float* Bt   = (const float*)d_in[1];
    const float* Mt   = (const float*)d_in[2];
    const float* Wqkv = (const float*)d_in[3];
    const float* Wred = (const float*)d_in[4];
    const float* Wrec = (const float*)d_in[5];
    float* out = (float*)d_out;

    unsigned char* p = (unsigned char*)d_ws;
    u16* xT = (u16*)p;            p += (size_t)3 * Bn * HWn * Cn * 2;   // 25.2 MB
    u16* Mm = (u16*)p;            p += (size_t)Bn * 256 * 768 * 2;      // 1.57 MB
    u16* CWp = (u16*)p;           p += (size_t)3 * MP * Cn * 2;         // 983 KB
    float* Psum = (float*)p;      p += (size_t)3 * MP * NCH * 4;        // 1.97 MB
    float* Pmax = (float*)p;      p += (size_t)3 * MP * NCH * 4;        // 1.97 MB
    float* vout = (float*)p;      p += (size_t)9 * Bn * CPn * 4;        // 9.2 KB

    prep         <<<dim3(256, Bn, 4), 256, 0, stream>>>(Tt, Bt, Mt, Wqkv, Wred, xT, CWp);
    redpool_fused<<<dim3(256),        256, 0, stream>>>(Tt, Bt, Mt, CWp, Psum, Pmax);
    attn_small   <<<9 * Bn,            64, 0, stream>>>(Psum, Pmax, vout);
    build_M      <<<dim3(768, Bn),    256, 0, stream>>>(Wqkv, Wrec, vout, Mm);
    final_mfma   <<<dim3(64, Bn),     256, 0, stream>>>(xT, Mm, out);
}